// Round 1
// 757.687 us; speedup vs baseline: 1.0346x; 1.0346x over previous
//
#include <hip/hip_runtime.h>
#include <hip/hip_bf16.h>

#define BF16 __hip_bfloat16
typedef short bf16x8 __attribute__((ext_vector_type(8)));
typedef float f32x4  __attribute__((ext_vector_type(4)));
typedef unsigned int u32;

#define MFMA16(a, b, c) __builtin_amdgcn_mfma_f32_16x16x32_bf16(a, b, c, 0, 0, 0)

// B=1, SV=2048, SA=512, S=2560, D=1024, H=16, DH=64, F=4096, L=2

__device__ __forceinline__ void async16(const void* g, void* l) {
  __builtin_amdgcn_global_load_lds(
      (const __attribute__((address_space(1))) u32*)g,
      (__attribute__((address_space(3))) u32*)l, 16, 0, 0);
}

__device__ __forceinline__ u32 pkbf(float a, float b) {
  union { BF16 h; unsigned short s; } ua, ub;
  ua.h = __float2bfloat16(a); ub.h = __float2bfloat16(b);
  return (u32)ua.s | ((u32)ub.s << 16);
}

// ---------------- weight transpose + f32->bf16 cast ----------------
__global__ __launch_bounds__(256) void wtrans(const float* __restrict__ W,
                                              BF16* __restrict__ WT, int K, int N,
                                              size_t outZ) {
  __shared__ float t[32][33];
  const float* Wm = W + (size_t)K * N * blockIdx.z;
  BF16* Tm = WT + outZ * blockIdx.z;
  int n0 = blockIdx.x * 32, k0 = blockIdx.y * 32;
  int tx = threadIdx.x & 31, ty = threadIdx.x >> 5;
#pragma unroll
  for (int i = 0; i < 4; i++)
    t[ty + 8 * i][tx] = Wm[(size_t)(k0 + ty + 8 * i) * N + n0 + tx];
  __syncthreads();
#pragma unroll
  for (int i = 0; i < 4; i++)
    Tm[(size_t)(n0 + ty + 8 * i) * K + k0 + tx] = __float2bfloat16(t[tx][ty + 8 * i]);
}

// ---------------- fused qkv bias pack ----------------
__global__ __launch_bounds__(256) void packb(const float* __restrict__ bq,
                                             const float* __restrict__ bk,
                                             const float* __restrict__ bv,
                                             float* __restrict__ bqkv) {
  int i = blockIdx.x * 256 + threadIdx.x;  // 4*3072
  int s = i / 3072, c = i - s * 3072;
  float v = (c < 1024) ? bq[s * 1024 + c]
          : (c < 2048) ? bk[s * 1024 + c - 1024]
                       : bv[s * 1024 + c - 2048];
  bqkv[i] = v;
}

// ---------------- LayerNorm * (1+sc) + sh -> bf16 ----------------
__global__ __launch_bounds__(256) void ln_mod(const float* __restrict__ x,
                                              BF16* __restrict__ out,
                                              const float* __restrict__ mod,
                                              const float* __restrict__ tmv,
                                              const float* __restrict__ tma,
                                              int l, int ish, int isc) {
  int r = blockIdx.x;
  int e = (r >= 2048) ? 1 : 0;
  const float* tm = e ? tma : tmv;
  const float* mo = mod + (size_t)((e * 2 + l) * 6) * 1024;
  float4 v = ((const float4*)(x + (size_t)r * 1024))[threadIdx.x];
  float s = v.x + v.y + v.z + v.w;
  float s2 = v.x * v.x + v.y * v.y + v.z * v.z + v.w * v.w;
#pragma unroll
  for (int off = 32; off >= 1; off >>= 1) {
    s += __shfl_down(s, off);
    s2 += __shfl_down(s2, off);
  }
  __shared__ float red[8];
  int lane = threadIdx.x & 63, w = threadIdx.x >> 6;
  if (lane == 0) { red[w] = s; red[4 + w] = s2; }
  __syncthreads();
  s = red[0] + red[1] + red[2] + red[3];
  s2 = red[4] + red[5] + red[6] + red[7];
  float mu = s * (1.f / 1024.f);
  float var = s2 * (1.f / 1024.f) - mu * mu;
  float inv = rsqrtf(var + 1e-6f);
  int c = threadIdx.x * 4;
  BF16* o = out + (size_t)r * 1024 + c;
  float xv[4] = {v.x, v.y, v.z, v.w};
#pragma unroll
  for (int k = 0; k < 4; k++) {
    float sc = mo[isc * 1024 + c + k] + tm[isc * 1024 + c + k];
    float sh = mo[ish * 1024 + c + k] + tm[ish * 1024 + c + k];
    o[k] = __float2bfloat16((xv[k] - mu) * inv * (1.f + sc) + sh);
  }
}

// ---------------- RMSNorm + gain + RoPE, reads fused qkv (stride 3072) ----------------
// Q rows are pre-scaled by 0.125*log2(e) so flash uses exp2 with raw dot products.
__global__ __launch_bounds__(256) void qk_post(const float* __restrict__ qkv,
                                               const float* __restrict__ gq,
                                               const float* __restrict__ gk,
                                               BF16* __restrict__ Qb, BF16* __restrict__ Kb,
                                               const float* __restrict__ vfreq,
                                               const float* __restrict__ afreq, int l) {
  int r = blockIdx.x;
  int which = blockIdx.y;
  const float* src = qkv + (size_t)r * 3072 + which * 1024;
  int e = (r >= 2048) ? 1 : 0;
  const float* g = (which ? gk : gq) + (size_t)(e * 2 + l) * 1024;
  BF16* dst = which ? Kb : Qb;
  const float* fr = e ? (afreq + (size_t)(r - 2048) * 32) : (vfreq + (size_t)r * 32);
  float4 v = ((const float4*)src)[threadIdx.x];
  float s2 = v.x * v.x + v.y * v.y + v.z * v.z + v.w * v.w;
#pragma unroll
  for (int off = 32; off >= 1; off >>= 1) s2 += __shfl_down(s2, off);
  __shared__ float red[4];
  int lane = threadIdx.x & 63, w = threadIdx.x >> 6;
  if (lane == 0) red[w] = s2;
  __syncthreads();
  s2 = red[0] + red[1] + red[2] + red[3];
  float inv = rsqrtf(s2 * (1.f / 1024.f) + 1e-6f);
  if (which == 0) inv *= 0.125f * 1.44269504f;  // fold softmax scale into Q
  int c = threadIdx.x * 4;
  float xe0 = v.x * inv * g[c], xo0 = v.y * inv * g[c + 1];
  float xe1 = v.z * inv * g[c + 2], xo1 = v.w * inv * g[c + 3];
  int p0 = (c & 63) >> 1;
  float c0, s0, c1, s1;
  __sincosf(fr[p0], &s0, &c0);
  __sincosf(fr[p0 + 1], &s1, &c1);
  int h = c >> 6;
  size_t o = ((size_t)h * 2560 + r) * 64 + (c & 63);
  dst[o + 0] = __float2bfloat16(xe0 * c0 - xo0 * s0);
  dst[o + 1] = __float2bfloat16(xe0 * s0 + xo0 * c0);
  dst[o + 2] = __float2bfloat16(xe1 * c1 - xo1 * s1);
  dst[o + 3] = __float2bfloat16(xe1 * s1 + xo1 * c1);
}

// ---------------- V (from qkv col 2048, stride 3072) -> V^T (H*DH, S) bf16 ----------------
__global__ __launch_bounds__(256) void vpost(const float* __restrict__ qkv,
                                             BF16* __restrict__ VT) {
  __shared__ float t[32][33];
  int r0 = blockIdx.x * 32, c0 = blockIdx.y * 32;
  int tx = threadIdx.x & 31, ty = threadIdx.x >> 5;
#pragma unroll
  for (int i = 0; i < 4; i++)
    t[ty + 8 * i][tx] = qkv[(size_t)(r0 + ty + 8 * i) * 3072 + 2048 + c0 + tx];
  __syncthreads();
#pragma unroll
  for (int i = 0; i < 4; i++)
    VT[(size_t)(c0 + ty + 8 * i) * 2560 + r0 + tx] = __float2bfloat16(t[tx][ty + 8 * i]);
}

// ---------------- GEMM v2: C = A(2560xK) * B^T(NxK), expert-aware, BK=64 ----------------
template <int EPI, int KS>
__global__ __launch_bounds__(256) void gemm2(const BF16* __restrict__ A,
                                             const BF16* __restrict__ Bw, size_t Bestride,
                                             const float* __restrict__ bias, int biasE,
                                             void* __restrict__ out, float* __restrict__ part,
                                             int N, int K) {
  __shared__ BF16 As[128 * 64];
  __shared__ BF16 Bs[128 * 64];
  int flat = blockIdx.x + blockIdx.y * gridDim.x;
  int xcd = flat & 7, slot = flat >> 3;
  int bx = slot % gridDim.x;
  int by = (slot / gridDim.x) * 8 + xcd;
  int m0 = bx * 128, n0 = by * 128;
  int e = (m0 >= 2048);
  const BF16* Ab = A + (size_t)m0 * K;
  const BF16* Bb = Bw + (e ? Bestride : 0) + (size_t)n0 * K;
  int kz0 = blockIdx.z * (K / KS), kz1 = kz0 + K / KS;
  int tid = threadIdx.x, lane = tid & 63, w = tid >> 6;
  int wr = w & 1, wc = w >> 1;
  int m15 = lane & 15, q4 = lane >> 4;
  int L[4], rS[4], cS[4];
#pragma unroll
  for (int i = 0; i < 4; i++) {
    L[i] = w * 256 + i * 64 + lane;
    rS[i] = L[i] >> 3;
    cS[i] = (L[i] & 7) ^ (rS[i] & 7);
  }
  f32x4 acc[4][4] = {};
  for (int k0 = kz0; k0 < kz1; k0 += 64) {
    __syncthreads();
#pragma unroll
    for (int i = 0; i < 4; i++) {
      async16(Ab + (size_t)rS[i] * K + k0 + cS[i] * 8, &As[L[i] * 8]);
      async16(Bb + (size_t)rS[i] * K + k0 + cS[i] * 8, &Bs[L[i] * 8]);
    }
    __syncthreads();
#pragma unroll
    for (int kk = 0; kk < 2; kk++) {
      int pos = ((kk * 4 + q4) ^ (m15 & 7)) * 8;
      bf16x8 af[4], bv[4];
#pragma unroll
      for (int i = 0; i < 4; i++) af[i] = *(const bf16x8*)&As[(wr * 64 + i * 16 + m15) * 64 + pos];
#pragma unroll
      for (int j = 0; j < 4; j++) bv[j] = *(const bf16x8*)&Bs[(wc * 64 + j * 16 + m15) * 64 + pos];
#pragma unroll
      for (int i = 0; i < 4; i++)
#pragma unroll
        for (int j = 0; j < 4; j++)
          acc[i][j] = MFMA16(af[i], bv[j], acc[i][j]);
    }
  }
#pragma unroll
  for (int i = 0; i < 4; i++) {
    int row = m0 + wr * 64 + 16 * i + q4 * 4;
#pragma unroll
    for (int j = 0; j < 4; j++) {
      int col = n0 + wc * 64 + 16 * j + m15;
      float b = (EPI == 3) ? 0.f : bias[e * biasE + col];
#pragma unroll
      for (int rg = 0; rg < 4; rg++) {
        float v = acc[i][j][rg] + b;
        size_t idx = (size_t)(row + rg) * N + col;
        if (EPI == 0) {
          ((float*)out)[idx] = v;
        } else if (EPI == 1) {
          float u = 0.7978845608f * (v + 0.044715f * v * v * v);
          ((BF16*)out)[idx] = __float2bfloat16(0.5f * v * (1.f + tanhf(u)));
        } else {
          part[(size_t)blockIdx.z * 2560 * N + idx] = v;
        }
      }
    }
  }
}

// ---------------- split-K combine + gated residual ----------------
template <int KS>
__global__ __launch_bounds__(256) void combine(const float* __restrict__ part,
                                               const float* __restrict__ biasL,
                                               const float* __restrict__ modp, int gi, int l,
                                               const float* __restrict__ tmv,
                                               const float* __restrict__ tma,
                                               const float* __restrict__ xin,
                                               float* __restrict__ xout) {
  int r = blockIdx.x, e = (r >= 2048) ? 1 : 0;
  int c = threadIdx.x * 4;
  float4 s = {0.f, 0.f, 0.f, 0.f};
#pragma unroll
  for (int z = 0; z < KS; z++) {
    float4 p = *(const float4*)&part[((size_t)z * 2560 + r) * 1024 + c];
    s.x += p.x; s.y += p.y; s.z += p.z; s.w += p.w;
  }
  float4 b = *(const float4*)&biasL[e * 2048 + c];
  const float* tm = e ? tma : tmv;
  float4 gm = *(const float4*)&modp[(size_t)((e * 2 + l) * 6 + gi) * 1024 + c];
  float4 gt = *(const float4*)&tm[gi * 1024 + c];
  float4 xi = *(const float4*)&xin[(size_t)r * 1024 + c];
  float4 o;
  o.x = xi.x + (gm.x + gt.x) * (s.x + b.x);
  o.y = xi.y + (gm.y + gt.y) * (s.y + b.y);
  o.z = xi.z + (gm.z + gt.z) * (s.z + b.z);
  o.w = xi.w + (gm.w + gt.w) * (s.w + b.w);
  *(float4*)&xout[(size_t)r * 1024 + c] = o;
}

// ---------------- flash v4: KV-split partials + defer-max + swizzled P ----------------
// Qb (pre-scaled),Kb: (H,S,DH) bf16; VT: (H,DH,S) bf16
// grid (40, 16, 2): z = KV half. Writes unnormalized O (f32) + (m,l) partials.
// LDS = 16K(K) + 16K(V) + 8K(P, XOR-swizzled stride 64) = 40960 -> 4 blocks/CU.
__global__ __launch_bounds__(256) void flash4(const BF16* __restrict__ Qb,
                                              const BF16* __restrict__ Kb,
                                              const BF16* __restrict__ VT,
                                              float* __restrict__ Op,
                                              float* __restrict__ ml) {
  const int S = 2560;
  __shared__ BF16 Ks[2][64 * 64];
  __shared__ BF16 Vs[2][64 * 64];
  __shared__ BF16 Ps[4][16 * 64];  // wave-private P, stride 64, XOR-swizzled
  int tid = threadIdx.x, lane = tid & 63, w = tid >> 6;
  int h = blockIdx.y, q0 = blockIdx.x * 64, kz = blockIdx.z;
  int m15 = lane & 15, q4 = lane >> 4;
  int actq = (q0 >= 2048);
  int nt = actq ? ((q0 >> 6) + 1) : 32;
  int tb = kz ? (nt >> 1) : 0;
  int te = kz ? nt : (nt >> 1);
  const BF16* qrow = Qb + ((size_t)h * S + q0 + w * 16 + m15) * 64;
  bf16x8 qf0 = *(const bf16x8*)(qrow + q4 * 8);
  bf16x8 qf1 = *(const bf16x8*)(qrow + 32 + q4 * 8);
  const BF16* kbase = Kb + (size_t)h * S * 64;
  const BF16* vbase = VT + (size_t)h * 64 * S;
  // staging: 64x64 tile = 512 chunks; 2 per thread
  int L0 = w * 128 + lane, L1 = L0 + 64;
  int r0 = L0 >> 3, c0 = (L0 & 7) ^ (r0 & 7);
  int r1 = L1 >> 3, c1 = (L1 & 7) ^ (r1 & 7);
  {
    const BF16* kg = kbase + (size_t)tb * 64 * 64;
    const BF16* vg = vbase + (size_t)tb * 64;
    async16(kg + (size_t)r0 * 64 + c0 * 8, &Ks[0][L0 * 8]);
    async16(kg + (size_t)r1 * 64 + c1 * 8, &Ks[0][L1 * 8]);
    async16(vg + (size_t)r0 * S + c0 * 8, &Vs[0][L0 * 8]);
    async16(vg + (size_t)r1 * S + c1 * 8, &Vs[0][L1 * 8]);
  }
  f32x4 oa[4] = {};
  float m_i = -1e30f, l_i = 0.f;
  int colq = q0 + w * 16 + m15;
  char* Pw = (char*)&Ps[w][0];
  int prow = m15 * 128;            // byte offset of this q's P row
  int pswz = (m15 & 7) << 4;       // XOR swizzle (bits 4-6 of row-local byte)
  int x0 = (q4 ^ (m15 & 7)) * 8, x1 = ((4 + q4) ^ (m15 & 7)) * 8;
  __syncthreads();
  for (int t = tb; t < te; t++) {
    int cur = (t - tb) & 1;
    if (t + 1 < te) {
      int nb = cur ^ 1;
      const BF16* kg = kbase + (size_t)(t + 1) * 64 * 64;
      const BF16* vg = vbase + (size_t)(t + 1) * 64;
      async16(kg + (size_t)r0 * 64 + c0 * 8, &Ks[nb][L0 * 8]);
      async16(kg + (size_t)r1 * 64 + c1 * 8, &Ks[nb][L1 * 8]);
      async16(vg + (size_t)r0 * S + c0 * 8, &Vs[nb][L0 * 8]);
      async16(vg + (size_t)r1 * S + c1 * 8, &Vs[nb][L1 * 8]);
    }
    // S^T = K * Q^T (col = q = m15, row = kv)
    f32x4 st[4];
#pragma unroll
    for (int jt = 0; jt < 4; jt++) {
      int row = (jt * 16 + m15) * 64;
      bf16x8 kf0 = *(const bf16x8*)&Ks[cur][row + x0];
      bf16x8 kf1 = *(const bf16x8*)&Ks[cur][row + x1];
      f32x4 zz = {};
      zz = MFMA16(kf0, qf0, zz);
      st[jt] = MFMA16(kf1, qf1, zz);
    }
    float mx = -1e30f;
    if (actq && t == nt - 1) {
#pragma unroll
      for (int jt = 0; jt < 4; jt++)
#pragma unroll
        for (int rg = 0; rg < 4; rg++) {
          int rowkv = t * 64 + jt * 16 + q4 * 4 + rg;
          if (rowkv > colq) st[jt][rg] = -1e30f;
          mx = fmaxf(mx, st[jt][rg]);
        }
    } else {
#pragma unroll
      for (int jt = 0; jt < 4; jt++) {
        mx = fmaxf(fmaxf(mx, st[jt][0]), st[jt][1]);  // v_max3
        mx = fmaxf(fmaxf(mx, st[jt][2]), st[jt][3]);
      }
    }
    mx = fmaxf(mx, __shfl_xor(mx, 16));
    mx = fmaxf(mx, __shfl_xor(mx, 32));
    // defer-max: only rescale when max grew by >8 (log2 domain; P bounded by 2^8)
    if (!__all(mx <= m_i + 8.f)) {
      float mn = fmaxf(m_i, mx);
      float al = exp2f(m_i - mn);
      m_i = mn;
      l_i *= al;
      float alr[4];
#pragma unroll
      for (int rg = 0; rg < 4; rg++) alr[rg] = __shfl(al, q4 * 4 + rg);
#pragma unroll
      for (int dt = 0; dt < 4; dt++)
#pragma unroll
        for (int rg = 0; rg < 4; rg++) oa[dt][rg] *= alr[rg];
    }
    float rs = 0.f;
#pragma unroll
    for (int jt = 0; jt < 4; jt++) {
      float p0 = exp2f(st[jt][0] - m_i), p1 = exp2f(st[jt][1] - m_i);
      float p2 = exp2f(st[jt][2] - m_i), p3 = exp2f(st[jt][3] - m_i);
      rs += (p0 + p1) + (p2 + p3);
      uint2 pr = {pkbf(p0, p1), pkbf(p2, p3)};
      *(uint2*)(Pw + prow + ((jt * 32 + q4 * 8) ^ pswz)) = pr;  // P[q][kv], b64
    }
    rs += __shfl_xor(rs, 16);
    rs += __shfl_xor(rs, 32);
    l_i += rs;
    // O += P * V  (A = P from wave-private swizzled LDS, B = V^T rows)
    bf16x8 pf0 = *(const bf16x8*)(Pw + prow + ((q4 * 16) ^ pswz));
    bf16x8 pf1 = *(const bf16x8*)(Pw + prow + ((64 + q4 * 16) ^ pswz));
#pragma unroll
    for (int dt = 0; dt < 4; dt++) {
      int vr = (dt * 16 + m15) * 64;
      bf16x8 vf0 = *(const bf16x8*)&Vs[cur][vr + x0];
      bf16x8 vf1 = *(const bf16x8*)&Vs[cur][vr + x1];
      oa[dt] = MFMA16(pf0, vf0, oa[dt]);
      oa[dt] = MFMA16(pf1, vf1, oa[dt]);
    }
    __syncthreads();
  }
  // store unnormalized partial O (f32) + m,l
  size_t ob = (((size_t)kz * 16 + h) * 40 + blockIdx.x) * 4096;
#pragma unroll
  for (int dt = 0; dt < 4; dt++)
#pragma unroll
    for (int rg = 0; rg < 4; rg++)
      Op[ob + (size_t)(w * 16 + q4 * 4 + rg) * 64 + dt * 16 + m15] = oa[dt][rg];
  if (q4 == 0) {
    float* mp = ml + (((size_t)kz * 16 + h) * 40 + blockIdx.x) * 128;
    mp[w * 16 + m15] = m_i;
    mp[64 + w * 16 + m15] = l_i;
  }
}

// ---------------- merge the two KV-half partials -> Obf bf16 ----------------
__global__ __launch_bounds__(256) void fcomb(const float* __restrict__ Op,
                                             const float* __restrict__ ml,
                                             BF16* __restrict__ O) {
  int qt = blockIdx.x, h = blockIdx.y;
  int q = threadIdx.x >> 2;          // 0..63
  int d0 = (threadIdx.x & 3) * 16;   // 16 floats per thread
  size_t tile = (size_t)h * 40 + qt;
  const size_t zO = (size_t)16 * 40 * 4096;
  const size_t zm = (size_t)16 * 40 * 128;
  size_t base = tile * 4096 + (size_t)q * 64 + d0;
  size_t mb = tile * 128 + q;
  float m0 = ml[mb], l0 = ml[mb + 64];
  float m1 = ml[zm + mb], l1 = ml[zm + mb + 64];
  float M = fmaxf(m0, m1);
  float a = exp2f(m0 - M), b = exp2f(m1 - M);
  float r = 1.f / (a * l0 + b * l1);
  a *= r; b *= r;
  BF16* orow = O + (size_t)(qt * 64 + q) * 1024 + h * 64 + d0;
#pragma unroll
  for (int i = 0; i < 4; i++) {
    float4 x0 = *(const float4*)&Op[base + i * 4];
    float4 x1 = *(const float4*)&Op[zO + base + i * 4];
    uint2 pr = {pkbf(a * x0.x + b * x1.x, a * x0.y + b * x1.y),
                pkbf(a * x0.z + b * x1.z, a * x0.w + b * x1.w)};
    *(uint2*)(orow + i * 4) = pr;
  }
}

// ---------------- host ----------------
extern "C" void kernel_launch(void* const* d_in, const int* in_sizes, int n_in,
                              void* d_out, int out_size, void* d_ws, size_t ws_size,
                              hipStream_t stream) {
  (void)in_sizes; (void)n_in; (void)out_size; (void)ws_size;
  const float* vid  = (const float*)d_in[0];
  const float* act  = (const float*)d_in[1];
  const float* vfr  = (const float*)d_in[2];
  const float* afr  = (const float*)d_in[3];
  const float* tmv  = (const float*)d_in[4];
  const float* tma  = (const float*)d_in[5];
  const float* Wq   = (const float*)d_in[6];
  const float* Wk   = (const float*)d_in[7];
  const float* Wv   = (const float*)d_in[8];
  const float* Wo   = (const float*)d_in[9];
  const float* bq   = (const float*)d_in[10];
  const float* bk   = (const float*)d_in[11];
  const float* bv   = (const float*)d_in[12];
  const float* bo   = (const float*)d_in[13];
  const float* gq   = (const float*)d_in[14];
  const float* gk   = (const float*)d_in[15];
  const float* modp = (const float*)d_in[16];
  const float* W1   = (const float*)d_in[17];
  const float* b1   = (const float*)d_in[18];
  const float* W2   = (const float*)d_in[19];
  const float* b2   = (const float*)d_in[20];

  char* p = (char*)d_ws;
  auto carve = [&](size_t bytes) {
    char* r = p;
    p += (bytes + 255) & ~(size_t)255;
    return r;
  };
  BF16* WqkvT = (BF16*)carve(4ull * 3072 * 1024 * 2);
  BF16* WoT   = (BF16*)carve(4ull * 1024 * 1024 * 2);
  BF16* W1T   = (BF16*)carve(4ull * 4096 * 1024 * 2);
  BF16* W2T   = (BF16*)carve(4ull * 1024 * 4096 * 2);
  float* bqkv = (float*)carve(4ull * 3072 * 4);
  float* x    = (float*)carve(2560ull * 1024 * 4);
  BF16* abf   = (BF16*)carve(2560ull * 1024 * 2);
  float* qkv  = (float*)carve(2560ull * 3072 * 4);
  BF16* Qb    = (BF16*)carve(2560ull * 1024 * 2);
  BF16* Kb    = (BF16*)carve(2560ull * 1024 * 2);
  float* part = qkv;  // aliases qkv/Qb/Kb region (dead when partials are live)
  float* Opar = qkv;                      // flash partials: 2*16*40*4096 f32 = 21.0MB
  float* mlb  = qkv + 2ull * 16 * 40 * 4096;  // + 655KB, still inside qkv region
  BF16* VTb   = (BF16*)carve(2560ull * 1024 * 2);
  BF16* Obf   = (BF16*)carve(2560ull * 1024 * 2);
  BF16* mibf  = (BF16*)carve(2560ull * 1024 * 2);
  BF16* hbf   = (BF16*)carve(2560ull * 4096 * 2);

  hipMemcpyAsync(x, vid, 2048ull * 1024 * 4, hipMemcpyDeviceToDevice, stream);
  hipMemcpyAsync(x + 2048ull * 1024, act, 512ull * 1024 * 4, hipMemcpyDeviceToDevice, stream);

  const size_t S3 = 3072ull * 1024;
  wtrans<<<dim3(32, 32, 4), 256, 0, stream>>>(Wq, WqkvT, 1024, 1024, S3);
  wtrans<<<dim3(32, 32, 4), 256, 0, stream>>>(Wk, WqkvT + 1024ull * 1024, 1024, 1024, S3);
  wtrans<<<dim3(32, 32, 4), 256, 0, stream>>>(Wv, WqkvT + 2048ull * 1024, 1024, 1024, S3);
  wtrans<<<dim3(32, 32, 4), 256, 0, stream>>>(Wo, WoT, 1024, 1024, 1024ull * 1024);
  wtrans<<<dim3(128, 32, 4), 256, 0, stream>>>(W1, W1T, 1024, 4096, 4096ull * 1024);
  wtrans<<<dim3(32, 128, 4), 256, 0, stream>>>(W2, W2T, 4096, 1024, 1024ull * 4096);
  packb<<<48, 256, 0, stream>>>(bq, bk, bv, bqkv);

  for (int l = 0; l < 2; l++) {
    ln_mod<<<2560, 256, 0, stream>>>(x, abf, modp, tmv, tma, l, 0, 1);
    gemm2<0, 1><<<dim3(20, 24, 1), 256, 0, stream>>>(
        abf, WqkvT + (size_t)l * S3, 2 * S3, bqkv + l * 3072, 6144, qkv, nullptr, 3072, 1024);
    qk_post<<<dim3(2560, 2), 256, 0, stream>>>(qkv, gq, gk, Qb, Kb, vfr, afr, l);
    vpost<<<dim3(80, 32), 256, 0, stream>>>(qkv, VTb);
    flash4<<<dim3(40, 16, 2), 256, 0, stream>>>(Qb, Kb, VTb, Opar, mlb);
    fcomb<<<dim3(40, 16), 256, 0, stream>>>(Opar, mlb, Obf);
    gemm2<3, 2><<<dim3(20, 8, 2), 256, 0, stream>>>(
        Obf, WoT + (size_t)l * 1024 * 1024, 2ull * 1024 * 1024, nullptr, 0, nullptr, part,
        1024, 1024);
    combine<2><<<2560, 256, 0, stream>>>(part, bo + l * 1024, modp, 2, l, tmv, tma, x, x);
    ln_mod<<<2560, 256, 0, stream>>>(x, mibf, modp, tmv, tma, l, 3, 4);
    gemm2<1, 1><<<dim3(20, 32, 1), 256, 0, stream>>>(
        mibf, W1T + (size_t)l * 4096 * 1024, 2ull * 4096 * 1024, b1 + l * 4096, 8192, hbf,
        nullptr, 4096, 1024);
    gemm2<3, 4><<<dim3(20, 8, 4), 256, 0, stream>>>(
        hbf, W2T + (size_t)l * 4096 * 1024, 2ull * 4096 * 1024, nullptr, 0, nullptr, part,
        1024, 4096);
    combine<4><<<2560, 256, 0, stream>>>(part, b2 + l * 1024, modp, 5, l, tmv, tma, x,
                                         (l == 1) ? (float*)d_out : x);
  }
}